// Round 11
// baseline (211.862 us; speedup 1.0000x reference)
//
#include <hip/hip_runtime.h>
#include <hip/hip_bf16.h>

// GraphSAGE 2-layer on MI355X.
//   h   = relu(mean_agg(x) @ W1l + b1 + x @ W1r)
//   out = mean_agg(h @ W2l) + b2 + h @ W2r          (aggregate AFTER transform: 64ch)
// R2: CSR-gather replaced atomic scatter (2302 -> 387 us).
// R3: bf16 gathers + MFMA bf16 GEMMs (387 -> 253 us).
// R4: bucketed 2-pass CSR build (253 -> 229 us).
// R5: build grid 64 -> 512 (229 -> 216 us).
// R6 FAILED: cooperative fusion; grid.sync() ~55 us each on 8 XCDs. Reverted.
// R7/R8: zero-atomic counts-matrix build + parallel scan (216 -> 194 us).
// R9 FAILED: gemm fusion with L2-STREAMED WEIGHTS regressed (weights must
//     stay in LDS). R10 reverted to two gemm_k (194 us).
// R11: fuse gather128 into gemm1 keeping weights in LDS: each lane gathers
//     exactly its own MFMA A-fragment channels into registers (bit-identical
//     sum order), -25.6 MB agg1b round-trip, -1 dispatch. LDS weight staging
//     overlapped with the gather (sync moved to just before the K-loop).

#define TBLOCK 256
#define MAXBUCK 256    // in-block total-scan requires NBUCK <= 256 (N <= 65536)
#define HGRID 512      // edge-processing blocks (2/CU)

typedef __attribute__((ext_vector_type(8))) short short8;
typedef __attribute__((ext_vector_type(4))) float f32x4;

__device__ __forceinline__ float bf2f(ushort u) {
    union { unsigned int i; float f; } v;
    v.i = (unsigned int)u << 16;
    return v.f;
}
__device__ __forceinline__ ushort f2bf(float f) {  // RTNE
    union { float f; unsigned int u; } v;
    v.f = f;
    unsigned int r = v.u + 0x7fffu + ((v.u >> 16) & 1u);
    return (ushort)(r >> 16);
}

// ---- per-block edge-index dtype detection (int32 vs int64) ----------------
// int64 little-endian with values < 2^31 => every odd int32 word is zero.
__device__ __forceinline__ int block_detect_is64(const int* __restrict__ edges) {
    __shared__ int sbad[4];
    int tid = threadIdx.x;
    int bad = 0;
    for (int i = tid; i < 2048; i += TBLOCK)
        if (edges[2 * i + 1] != 0) bad = 1;
    unsigned long long b = __ballot(bad);
    if ((tid & 63) == 0) sbad[tid >> 6] = (b != 0) ? 1 : 0;
    __syncthreads();
    int flag = (sbad[0] | sbad[1] | sbad[2] | sbad[3]) ? 0 : 1;
    __syncthreads();
    return flag;
}

__device__ __forceinline__ int load_src(const int* e, long long i, int E, int is64) {
    return is64 ? e[2 * i] : e[i];
}
__device__ __forceinline__ int load_dst(const int* e, long long i, int E, int is64) {
    return is64 ? e[2 * (long long)E + 2 * i] : e[(long long)E + i];
}

// ---- in-block inclusive scan of bucket totals (NBUCK <= 256) --------------
__device__ __forceinline__ void scan_total(const int* __restrict__ total, int NBUCK,
                                           int* __restrict__ s) {
    int t = threadIdx.x;
    s[t] = (t < NBUCK) ? total[t] : 0;
    __syncthreads();
    for (int off = 1; off < TBLOCK; off <<= 1) {
        int xv = (t >= off) ? s[t - off] : 0;
        __syncthreads();
        s[t] += xv;
        __syncthreads();
    }
    // s[t] now holds inclusive prefix sums
}

// ===========================================================================
// histprep_k: blocks [0,HGRID) do the bucket histogram (bucket = dst>>8) and
// store per-block counts NON-ATOMICALLY to counts[j*HGRID + b] (no pre-zero
// needed). Blocks >= HGRID do prep: x -> bf16 xb, weight transpose/concat.
// wc[((k>>3)*128 + n)*8 + (k&7)] = W[k][n] (chunk-major for MFMA B-frags)
// wc1: K=256 = [W1l; W1r], N=128.  wc2: K=128, N=128 = [W2l | W2r].
// ===========================================================================
__global__ __launch_bounds__(TBLOCK) void histprep_k(
    const float* __restrict__ x,
    const float* __restrict__ W1l, const float* __restrict__ W1r,
    const float* __restrict__ W2l, const float* __restrict__ W2r,
    const int* __restrict__ edges, int E, int NBUCK,
    ushort* __restrict__ xb, ushort* __restrict__ wc1, ushort* __restrict__ wc2,
    int* __restrict__ counts, int n8, int nxb) {
    __shared__ int lh[MAXBUCK];
    const int b = blockIdx.x;
    const int t = threadIdx.x;
    if (b < HGRID) {
        const int is64 = block_detect_is64(edges);
        for (int i = t; i < NBUCK; i += TBLOCK) lh[i] = 0;
        __syncthreads();
        const int per = (E + HGRID - 1) / HGRID;
        const int b0 = b * per, b1 = min(E, b0 + per);
        for (int i = b0 + t; i < b1; i += TBLOCK)
            atomicAdd(&lh[load_dst(edges, i, E, is64) >> 8], 1);
        __syncthreads();
        for (int j = t; j < NBUCK; j += TBLOCK)
            counts[j * HGRID + b] = lh[j];
    } else {
        int pb = b - HGRID;
        if (pb < nxb) {
            int i = pb * TBLOCK + t;
            if (i >= n8) return;
            const float4* p = (const float4*)x + (size_t)i * 2;
            float4 a = p[0], bb = p[1];
            short8 o;
            o[0] = f2bf(a.x); o[1] = f2bf(a.y); o[2] = f2bf(a.z); o[3] = f2bf(a.w);
            o[4] = f2bf(bb.x); o[5] = f2bf(bb.y); o[6] = f2bf(bb.z); o[7] = f2bf(bb.w);
            *(short8*)(xb + (size_t)i * 8) = o;
        } else {
            int i = (pb - nxb) * TBLOCK + t;
            if (i < 32768) {
                int j = i & 7;
                int rest = i >> 3;
                int n = rest & 127;
                int k = ((rest >> 7) << 3) | j;
                float w = (k < 128) ? W1l[k * 128 + n] : W1r[(k - 128) * 128 + n];
                wc1[i] = f2bf(w);
            } else if (i < 49152) {
                int i2 = i - 32768;
                int j = i2 & 7;
                int rest = i2 >> 3;
                int n = rest & 127;
                int k = ((rest >> 7) << 3) | j;
                float w = (n < 64) ? W2l[k * 64 + n] : W2r[k * 64 + (n - 64)];
                wc2[i2] = f2bf(w);
            }
        }
    }
}

// ===========================================================================
// scanA_k: one block per bucket. Parallel exclusive scan of the bucket's
// HGRID per-block counts (2/thread via LDS), rewrite row in place as LOCAL
// exclusive prefixes, write bucket total.
// ===========================================================================
__global__ __launch_bounds__(TBLOCK) void scanA_k(int* __restrict__ counts,
                                                  int* __restrict__ total) {
    __shared__ int s[TBLOCK];
    const int j = blockIdx.x;
    const int t = threadIdx.x;
    int* row = counts + (size_t)j * HGRID;
    int v0 = row[2 * t];
    int v1 = row[2 * t + 1];
    s[t] = v0 + v1;
    __syncthreads();
    for (int off = 1; off < TBLOCK; off <<= 1) {
        int xv = (t >= off) ? s[t - off] : 0;
        __syncthreads();
        s[t] += xv;
        __syncthreads();
    }
    int excl = (t == 0) ? 0 : s[t - 1];
    row[2 * t] = excl;
    row[2 * t + 1] = excl + v0;
    if (t == TBLOCK - 1) total[j] = s[t];
}

// ===========================================================================
// scatterA_k: block b's start offset for bucket j = scan(total)[j] (computed
// in LDS) + counts[j][b] (no global atomics). Writes packed =
// src | (dst&255)<<24 into contiguous per-bucket runs.
// ===========================================================================
__global__ __launch_bounds__(TBLOCK) void scatterA_k(const int* __restrict__ edges, int E,
                                                     const int* __restrict__ counts,
                                                     const int* __restrict__ total,
                                                     unsigned int* __restrict__ packed,
                                                     int NBUCK) {
    const int is64 = block_detect_is64(edges);
    __shared__ int s[TBLOCK];
    __shared__ int lb[MAXBUCK];
    __shared__ int lh[MAXBUCK];
    const int b = blockIdx.x;
    const int t = threadIdx.x;
    scan_total(total, NBUCK, s);
    if (t < NBUCK) {
        int excl = (t == 0) ? 0 : s[t - 1];
        lb[t] = excl + counts[t * HGRID + b];
        lh[t] = 0;
    }
    __syncthreads();
    const int per = (E + HGRID - 1) / HGRID;
    const int b0 = b * per, b1 = min(E, b0 + per);
    for (int i = b0 + t; i < b1; i += TBLOCK) {
        int sv = load_src(edges, i, E, is64);
        int d = load_dst(edges, i, E, is64);
        int bk = d >> 8;
        int pos = lb[bk] + atomicAdd(&lh[bk], 1);
        packed[pos] = (unsigned int)sv | ((unsigned int)(d & 255) << 24);
    }
}

// ---- per-bucket CSR finalize (one workgroup per bucket) -------------------
__global__ __launch_bounds__(TBLOCK) void buildB_k(const unsigned int* __restrict__ packed,
                                                   const int* __restrict__ total,
                                                   int* __restrict__ offs,
                                                   int* __restrict__ degi,
                                                   float* __restrict__ invdeg,
                                                   int* __restrict__ csr, int N, int NBUCK) {
    __shared__ int s[TBLOCK];
    __shared__ int cnt[TBLOCK], scn[TBLOCK], cur[TBLOCK];
    int t = threadIdx.x;
    int bucket = blockIdx.x;
    scan_total(total, NBUCK, s);
    int e0 = (bucket == 0) ? 0 : s[bucket - 1];
    int e1 = s[bucket];
    cnt[t] = 0;
    cur[t] = 0;
    __syncthreads();
    for (int i = e0 + t; i < e1; i += TBLOCK)
        atomicAdd(&cnt[packed[i] >> 24], 1);
    __syncthreads();
    scn[t] = cnt[t];
    __syncthreads();
    for (int off = 1; off < TBLOCK; off <<= 1) {
        int x = (t >= off) ? scn[t - off] : 0;
        __syncthreads();
        scn[t] += x;
        __syncthreads();
    }
    int excl = (t == 0) ? 0 : scn[t - 1];
    int node = bucket * 256 + t;
    if (node < N) {
        offs[node] = e0 + excl;
        degi[node] = cnt[t];
        invdeg[node] = 1.0f / fmaxf((float)cnt[t], 1.0f);
    }
    __syncthreads();
    cnt[t] = excl;               // reuse as per-node exclusive base
    __syncthreads();
    for (int i = e0 + t; i < e1; i += TBLOCK) {
        unsigned int p = packed[i];
        int nl = p >> 24;
        int pos = e0 + cnt[nl] + atomicAdd(&cur[nl], 1);
        csr[pos] = (int)(p & 0xFFFFFFu);
    }
}

// ---- gather-aggregate over bf16 features (layer 2 only: C=64, ACCUM) ------
// outF[n][:] += invdeg[n] * sum feat[src]
template <int C, bool ACCUM>
__global__ __launch_bounds__(TBLOCK) void gatherb_k(const ushort* __restrict__ feat,
                                                    const int* __restrict__ csr,
                                                    const int* __restrict__ offs,
                                                    const int* __restrict__ degi,
                                                    const float* __restrict__ invdeg,
                                                    ushort* __restrict__ outB,
                                                    float* __restrict__ outF, int N) {
    constexpr int G = C / 8;                  // lanes per node, 16B bf16x8 each
    constexpr int NPB = TBLOCK / G;
    int n = blockIdx.x * NPB + threadIdx.x / G;
    if (n >= N) return;
    int lane = threadIdx.x % G;
    int c = lane * 8;
    int s0 = offs[n];
    int d = degi[n];
    float acc[8] = {0.f, 0.f, 0.f, 0.f, 0.f, 0.f, 0.f, 0.f};
    for (int base = 0; base < d; base += G) {
        int rem = d - base;
        int my = (lane < rem) ? csr[s0 + base + lane] : 0;
        if (rem >= G) {
#pragma unroll
            for (int j = 0; j < G; j++) {
                int s = __shfl(my, j, G);
                short8 v = *(const short8*)(feat + (size_t)s * C + c);
#pragma unroll
                for (int q = 0; q < 8; q++) acc[q] += bf2f((ushort)v[q]);
            }
        } else {
            for (int j = 0; j < rem; j++) {
                int s = __shfl(my, j, G);
                short8 v = *(const short8*)(feat + (size_t)s * C + c);
#pragma unroll
                for (int q = 0; q < 8; q++) acc[q] += bf2f((ushort)v[q]);
            }
        }
    }
    float sc = invdeg[n];
    if (ACCUM) {
        float* o = outF + (size_t)n * C + c;
        float4 p0 = *(float4*)o;
        float4 p1 = *(float4*)(o + 4);
        p0.x += sc * acc[0]; p0.y += sc * acc[1]; p0.z += sc * acc[2]; p0.w += sc * acc[3];
        p1.x += sc * acc[4]; p1.y += sc * acc[5]; p1.z += sc * acc[6]; p1.w += sc * acc[7];
        *(float4*)o = p0;
        *(float4*)(o + 4) = p1;
    } else {
        short8 o;
#pragma unroll
        for (int q = 0; q < 8; q++) o[q] = f2bf(sc * acc[q]);
        *(short8*)(outB + (size_t)n * C + c) = o;
    }
}

// ===========================================================================
// gg1_k: FUSED gather128 + gemm1.  hb = bf16(relu([mean_agg(xb) | xb] @ wc1 + b1))
// Weights LDS-resident (64 KB, staged before the gather, synced after).
// Each lane gathers exactly its own MFMA A-fragment channels into registers:
// 2 rows (t=0,1: m = m0+t*16+l16) x 4 chunks (channels c*32+quad*8..+7),
// accumulating neighbors in csr order (bit-identical to the standalone
// gather+agg1b path), scales by invdeg, packs to bf16 frags.
// mfma_f32_16x16x32_bf16 layouts (m89/m91):
//   A frag: lane L holds A[m=L&15][k=(L>>4)*8+j]; B frag: B[k=(L>>4)*8+j][n=L&15]
//   C/D: reg r -> row=(L>>4)*4+r, col=L&15
// ===========================================================================
__global__ __launch_bounds__(TBLOCK) void gg1_k(const ushort* __restrict__ xb,
                                                const int* __restrict__ csr,
                                                const int* __restrict__ offs,
                                                const int* __restrict__ degi,
                                                const float* __restrict__ invdeg,
                                                const ushort* __restrict__ wc1,
                                                const float* __restrict__ b1,
                                                ushort* __restrict__ hb, int N) {
    __shared__ __align__(16) ushort sW[256 * 128];   // 64 KB
    for (int i = threadIdx.x * 8; i < 256 * 128; i += TBLOCK * 8)
        *(short8*)&sW[i] = *(const short8*)&wc1[i];
    // no sync yet — overlap weight staging with the gather phase

    const int wave = threadIdx.x >> 6;
    const int lane = threadIdx.x & 63;
    const int quad = lane >> 4;
    const int l16 = lane & 15;
    const int m0 = blockIdx.x * 128 + wave * 32;
    const int cq = quad * 8;

    // ---- gather phase: per-lane A-fragment accumulation ----
    short8 aagg[2][4];
#pragma unroll
    for (int t = 0; t < 2; t++) {
        int m = m0 + t * 16 + l16;
        if (m > N - 1) m = N - 1;
        int s0 = offs[m];
        int d = degi[m];
        float ga[4][8];
#pragma unroll
        for (int c = 0; c < 4; c++)
#pragma unroll
            for (int q = 0; q < 8; q++) ga[c][q] = 0.f;
        for (int e = 0; e < d; e++) {
            int s = csr[s0 + e];
            const ushort* row = xb + (size_t)s * 128 + cq;
            short8 v0 = *(const short8*)(row);
            short8 v1 = *(const short8*)(row + 32);
            short8 v2 = *(const short8*)(row + 64);
            short8 v3 = *(const short8*)(row + 96);
#pragma unroll
            for (int q = 0; q < 8; q++) {
                ga[0][q] += bf2f((ushort)v0[q]);
                ga[1][q] += bf2f((ushort)v1[q]);
                ga[2][q] += bf2f((ushort)v2[q]);
                ga[3][q] += bf2f((ushort)v3[q]);
            }
        }
        float iv = invdeg[m];
#pragma unroll
        for (int c = 0; c < 4; c++)
#pragma unroll
            for (int q = 0; q < 8; q++) aagg[t][c][q] = f2bf(ga[c][q] * iv);
    }
    __syncthreads();   // sW now needed

    // ---- MFMA phase: K=256 ([agg | xb]) ----
    f32x4 acc[2][8];
#pragma unroll
    for (int t = 0; t < 2; t++)
#pragma unroll
        for (int nt = 0; nt < 8; nt++) acc[t][nt] = (f32x4){0.f, 0.f, 0.f, 0.f};

    // K 0..127: A-frags from gathered registers
#pragma unroll
    for (int kb = 0; kb < 128; kb += 32) {
        int c = kb >> 5;
        int k = kb + cq;
#pragma unroll
        for (int nt = 0; nt < 8; nt++) {
            short8 b = *(const short8*)&sW[((k >> 3) * 128 + nt * 16 + l16) * 8];
            acc[0][nt] = __builtin_amdgcn_mfma_f32_16x16x32_bf16(aagg[0][c], b, acc[0][nt], 0, 0, 0);
            acc[1][nt] = __builtin_amdgcn_mfma_f32_16x16x32_bf16(aagg[1][c], b, acc[1][nt], 0, 0, 0);
        }
    }
    // K 128..255: A-frags from xb directly
#pragma unroll
    for (int kb = 128; kb < 256; kb += 32) {
        int k = kb + cq;
        short8 a[2];
#pragma unroll
        for (int t = 0; t < 2; t++) {
            int m = m0 + t * 16 + l16;
            if (m > N - 1) m = N - 1;
            a[t] = *(const short8*)(xb + (size_t)m * 128 + (k - 128));
        }
#pragma unroll
        for (int nt = 0; nt < 8; nt++) {
            short8 b = *(const short8*)&sW[((k >> 3) * 128 + nt * 16 + l16) * 8];
            acc[0][nt] = __builtin_amdgcn_mfma_f32_16x16x32_bf16(a[0], b, acc[0][nt], 0, 0, 0);
            acc[1][nt] = __builtin_amdgcn_mfma_f32_16x16x32_bf16(a[1], b, acc[1][nt], 0, 0, 0);
        }
    }

    // ---- epilogue: hb = bf16(relu(acc + b1)) ----
#pragma unroll
    for (int t = 0; t < 2; t++)
#pragma unroll
        for (int r = 0; r < 4; r++) {
            int m = m0 + t * 16 + quad * 4 + r;
            if (m >= N) continue;
#pragma unroll
            for (int nt = 0; nt < 8; nt++) {
                int n = nt * 16 + l16;
                float v = fmaxf(acc[t][nt][r] + b1[n], 0.f);
                hb[(size_t)m * 128 + n] = f2bf(v);
            }
        }
}

// ---- MFMA bf16 GEMM layer 2: [N x 128] @ [128 x 128], weights in LDS ------
// n<64 -> t2b = bf16(acc); n>=64 -> out = acc + b2[n-64] (fp32)
__global__ __launch_bounds__(TBLOCK) void gemm2_k(const ushort* __restrict__ A0,
                                                  const ushort* __restrict__ wc,
                                                  const float* __restrict__ bias,
                                                  ushort* __restrict__ outB,
                                                  float* __restrict__ outF, int N) {
    constexpr int KTOT = 128;
    __shared__ __align__(16) ushort sW[KTOT * 128];
    for (int i = threadIdx.x * 8; i < KTOT * 128; i += TBLOCK * 8)
        *(short8*)&sW[i] = *(const short8*)&wc[i];
    __syncthreads();

    const int wave = threadIdx.x >> 6;
    const int lane = threadIdx.x & 63;
    const int quad = lane >> 4;
    const int l16 = lane & 15;
    const int m0 = (blockIdx.x * 4 + wave) * 32;
    if (m0 >= N) return;

    f32x4 acc[2][8];
#pragma unroll
    for (int t = 0; t < 2; t++)
#pragma unroll
        for (int nt = 0; nt < 8; nt++) acc[t][nt] = (f32x4){0.f, 0.f, 0.f, 0.f};

    const int k0q = quad * 8;
#pragma unroll
    for (int kb = 0; kb < KTOT; kb += 32) {
        int k = kb + k0q;
        short8 a[2];
#pragma unroll
        for (int t = 0; t < 2; t++) {
            int m = m0 + t * 16 + l16;
            if (m > N - 1) m = N - 1;
            a[t] = *(const short8*)(A0 + (size_t)m * 128 + k);
        }
#pragma unroll
        for (int nt = 0; nt < 8; nt++) {
            short8 b = *(const short8*)&sW[((k >> 3) * 128 + nt * 16 + l16) * 8];
            acc[0][nt] = __builtin_amdgcn_mfma_f32_16x16x32_bf16(a[0], b, acc[0][nt], 0, 0, 0);
            acc[1][nt] = __builtin_amdgcn_mfma_f32_16x16x32_bf16(a[1], b, acc[1][nt], 0, 0, 0);
        }
    }

#pragma unroll
    for (int t = 0; t < 2; t++) {
#pragma unroll
        for (int r = 0; r < 4; r++) {
            int m = m0 + t * 16 + quad * 4 + r;
            if (m >= N) continue;
#pragma unroll
            for (int nt = 0; nt < 8; nt++) {
                int n = nt * 16 + l16;
                float v = acc[t][nt][r];
                if (n < 64) outB[(size_t)m * 64 + n] = f2bf(v);
                else outF[(size_t)m * 64 + (n - 64)] = v + bias[n - 64];
            }
        }
    }
}

extern "C" void kernel_launch(void* const* d_in, const int* in_sizes, int n_in,
                              void* d_out, int out_size, void* d_ws, size_t ws_size,
                              hipStream_t stream) {
    const float* x = (const float*)d_in[0];
    const int* edges = (const int*)d_in[1];
    const float* W1l = (const float*)d_in[2];
    const float* b1 = (const float*)d_in[3];
    const float* W1r = (const float*)d_in[4];
    const float* W2l = (const float*)d_in[5];
    const float* b2 = (const float*)d_in[6];
    const float* W2r = (const float*)d_in[7];
    float* out = (float*)d_out;

    const int N = in_sizes[0] / 128;   // 50000
    const int E = in_sizes[1] / 2;     // 800000
    const int Na = (N + 63) & ~63;
    const int NBUCK = (N + 255) >> 8;  // 196 (in-block scans require <= 256)
    const int n8 = N * 128 / 8;
    const int nxb = (n8 + TBLOCK - 1) / TBLOCK;

    // ---- workspace layout (bytes, 256B-aligned regions) ----
    char* WS = (char*)d_ws;
    size_t off = 0;
    auto alloc = [&](size_t bytes) {
        void* p = WS + off;
        off = (off + bytes + 255) & ~(size_t)255;
        return p;
    };
    int* counts = (int*)alloc((size_t)MAXBUCK * HGRID * 4);  // per-(bucket,block)
    int* total = (int*)alloc((size_t)MAXBUCK * 4);
    int* offs = (int*)alloc((size_t)Na * 4);
    int* degi = (int*)alloc((size_t)Na * 4);
    float* invdeg = (float*)alloc((size_t)Na * 4);
    unsigned int* packed = (unsigned int*)alloc((size_t)E * 4);
    int* csr = (int*)alloc((size_t)E * 4);
    ushort* xb = (ushort*)alloc((size_t)N * 128 * 2);
    ushort* hb = (ushort*)alloc((size_t)N * 128 * 2);
    ushort* t2b = (ushort*)alloc((size_t)N * 64 * 2);
    ushort* wc1 = (ushort*)alloc(32768 * 2);
    ushort* wc2 = (ushort*)alloc(16384 * 2);

    // ---- CSR build (no memset, no global atomics) + prep -----------------
    histprep_k<<<HGRID + nxb + 192, TBLOCK, 0, stream>>>(
        x, W1l, W1r, W2l, W2r, edges, E, NBUCK, xb, wc1, wc2, counts, n8, nxb);
    scanA_k<<<NBUCK, TBLOCK, 0, stream>>>(counts, total);
    scatterA_k<<<HGRID, TBLOCK, 0, stream>>>(edges, E, counts, total, packed, NBUCK);
    buildB_k<<<NBUCK, TBLOCK, 0, stream>>>(packed, total, offs, degi, invdeg, csr, N, NBUCK);

    // fused layer 1: hb = bf16(relu([mean_agg(xb) | xb] @ wc1 + b1))
    gg1_k<<<(N + 127) / 128, TBLOCK, 0, stream>>>(
        xb, csr, offs, degi, invdeg, wc1, b1, hb, N);

    // layer 2: t2b = bf16(hb @ W2l); out = hb @ W2r + b2
    gemm2_k<<<(N + 127) / 128, TBLOCK, 0, stream>>>(
        hb, wc2, b2, t2b, out, N);
    // out += mean_agg(t2b)
    gatherb_k<64, true><<<(N + 31) / 32, TBLOCK, 0, stream>>>(
        t2b, csr, offs, degi, invdeg, nullptr, out, N);
}

// Round 12
// 194.153 us; speedup vs baseline: 1.0912x; 1.0912x over previous
//
#include <hip/hip_runtime.h>
#include <hip/hip_bf16.h>

// GraphSAGE 2-layer on MI355X.
//   h   = relu(mean_agg(x) @ W1l + b1 + x @ W1r)
//   out = mean_agg(h @ W2l) + b2 + h @ W2r          (aggregate AFTER transform: 64ch)
// R2: CSR-gather replaced atomic scatter (2302 -> 387 us).
// R3: bf16 gathers + MFMA bf16 GEMMs (387 -> 253 us).
// R4/R5: bucketed CSR build, wide grid (253 -> 216 us).
// R6 FAILED: cooperative fusion; grid.sync() ~55 us each on 8 XCDs.
// R7/R8: zero-atomic counts-matrix build + parallel scan (216 -> 194 us).
// R9 FAILED: gemm with L2-streamed weights (weights must be LDS-resident).
// R11 FAILED: gather fused into gemm block (2 blk/CU occupancy + uncoalesced
//     per-lane gather = 67 us). Gather wants high occupancy + no LDS.
// R12: R10 structure + ROLE-SPLIT overlap: the independent x@W1r root GEMM
//     rides in the scatterA launch (blocks 0..RB-1 gemm / RB.. scatter),
//     hiding ~8 us of GEMM under the latency-bound edge pass. gemm1 shrinks
//     to K=128 (agg@W1l + hb base + relu).

#define TBLOCK 256
#define MAXBUCK 256    // in-block total-scan requires NBUCK <= 256 (N <= 65536)
#define HGRID 512      // edge-processing blocks (2/CU)

typedef __attribute__((ext_vector_type(8))) short short8;
typedef __attribute__((ext_vector_type(4))) float f32x4;

__device__ __forceinline__ float bf2f(ushort u) {
    union { unsigned int i; float f; } v;
    v.i = (unsigned int)u << 16;
    return v.f;
}
__device__ __forceinline__ ushort f2bf(float f) {  // RTNE
    union { float f; unsigned int u; } v;
    v.f = f;
    unsigned int r = v.u + 0x7fffu + ((v.u >> 16) & 1u);
    return (ushort)(r >> 16);
}

// ---- per-block edge-index dtype detection (int32 vs int64) ----------------
// int64 little-endian with values < 2^31 => every odd int32 word is zero.
__device__ __forceinline__ int block_detect_is64(const int* __restrict__ edges) {
    __shared__ int sbad[4];
    int tid = threadIdx.x;
    int bad = 0;
    for (int i = tid; i < 2048; i += TBLOCK)
        if (edges[2 * i + 1] != 0) bad = 1;
    unsigned long long b = __ballot(bad);
    if ((tid & 63) == 0) sbad[tid >> 6] = (b != 0) ? 1 : 0;
    __syncthreads();
    int flag = (sbad[0] | sbad[1] | sbad[2] | sbad[3]) ? 0 : 1;
    __syncthreads();
    return flag;
}

__device__ __forceinline__ int load_src(const int* e, long long i, int E, int is64) {
    return is64 ? e[2 * i] : e[i];
}
__device__ __forceinline__ int load_dst(const int* e, long long i, int E, int is64) {
    return is64 ? e[2 * (long long)E + 2 * i] : e[(long long)E + i];
}

// ---- in-block inclusive scan of bucket totals (NBUCK <= 256) --------------
__device__ __forceinline__ void scan_total(const int* __restrict__ total, int NBUCK,
                                           int* __restrict__ s) {
    int t = threadIdx.x;
    s[t] = (t < NBUCK) ? total[t] : 0;
    __syncthreads();
    for (int off = 1; off < TBLOCK; off <<= 1) {
        int xv = (t >= off) ? s[t - off] : 0;
        __syncthreads();
        s[t] += xv;
        __syncthreads();
    }
    // s[t] now holds inclusive prefix sums
}

// ===========================================================================
// histprep_k: blocks [0,HGRID) do the bucket histogram (bucket = dst>>8) and
// store per-block counts NON-ATOMICALLY to counts[j*HGRID + b] (no pre-zero
// needed). Blocks >= HGRID do prep: x -> bf16 xb, weight transpose/concat.
// wc[((k>>3)*128 + n)*8 + (k&7)] = W[k][n] (chunk-major for MFMA B-frags)
// wc1: K=256 = [W1l; W1r], N=128.  wc2: K=128, N=128 = [W2l | W2r].
// ===========================================================================
__global__ __launch_bounds__(TBLOCK) void histprep_k(
    const float* __restrict__ x,
    const float* __restrict__ W1l, const float* __restrict__ W1r,
    const float* __restrict__ W2l, const float* __restrict__ W2r,
    const int* __restrict__ edges, int E, int NBUCK,
    ushort* __restrict__ xb, ushort* __restrict__ wc1, ushort* __restrict__ wc2,
    int* __restrict__ counts, int n8, int nxb) {
    __shared__ int lh[MAXBUCK];
    const int b = blockIdx.x;
    const int t = threadIdx.x;
    if (b < HGRID) {
        const int is64 = block_detect_is64(edges);
        for (int i = t; i < NBUCK; i += TBLOCK) lh[i] = 0;
        __syncthreads();
        const int per = (E + HGRID - 1) / HGRID;
        const int b0 = b * per, b1 = min(E, b0 + per);
        for (int i = b0 + t; i < b1; i += TBLOCK)
            atomicAdd(&lh[load_dst(edges, i, E, is64) >> 8], 1);
        __syncthreads();
        for (int j = t; j < NBUCK; j += TBLOCK)
            counts[j * HGRID + b] = lh[j];
    } else {
        int pb = b - HGRID;
        if (pb < nxb) {
            int i = pb * TBLOCK + t;
            if (i >= n8) return;
            const float4* p = (const float4*)x + (size_t)i * 2;
            float4 a = p[0], bb = p[1];
            short8 o;
            o[0] = f2bf(a.x); o[1] = f2bf(a.y); o[2] = f2bf(a.z); o[3] = f2bf(a.w);
            o[4] = f2bf(bb.x); o[5] = f2bf(bb.y); o[6] = f2bf(bb.z); o[7] = f2bf(bb.w);
            *(short8*)(xb + (size_t)i * 8) = o;
        } else {
            int i = (pb - nxb) * TBLOCK + t;
            if (i < 32768) {
                int j = i & 7;
                int rest = i >> 3;
                int n = rest & 127;
                int k = ((rest >> 7) << 3) | j;
                float w = (k < 128) ? W1l[k * 128 + n] : W1r[(k - 128) * 128 + n];
                wc1[i] = f2bf(w);
            } else if (i < 49152) {
                int i2 = i - 32768;
                int j = i2 & 7;
                int rest = i2 >> 3;
                int n = rest & 127;
                int k = ((rest >> 7) << 3) | j;
                float w = (n < 64) ? W2l[k * 64 + n] : W2r[k * 64 + (n - 64)];
                wc2[i2] = f2bf(w);
            }
        }
    }
}

// ===========================================================================
// scanA_k: one block per bucket. Parallel exclusive scan of the bucket's
// HGRID per-block counts (2/thread via LDS), rewrite row in place as LOCAL
// exclusive prefixes, write bucket total.
// ===========================================================================
__global__ __launch_bounds__(TBLOCK) void scanA_k(int* __restrict__ counts,
                                                  int* __restrict__ total) {
    __shared__ int s[TBLOCK];
    const int j = blockIdx.x;
    const int t = threadIdx.x;
    int* row = counts + (size_t)j * HGRID;
    int v0 = row[2 * t];
    int v1 = row[2 * t + 1];
    s[t] = v0 + v1;
    __syncthreads();
    for (int off = 1; off < TBLOCK; off <<= 1) {
        int xv = (t >= off) ? s[t - off] : 0;
        __syncthreads();
        s[t] += xv;
        __syncthreads();
    }
    int excl = (t == 0) ? 0 : s[t - 1];
    row[2 * t] = excl;
    row[2 * t + 1] = excl + v0;
    if (t == TBLOCK - 1) total[j] = s[t];
}

// ===========================================================================
// scatroot_k (role-split, overlapped):
//   blocks [0, RB):       root GEMM  hb = bf16(xb @ W1r + b1)   (no relu yet)
//                         W1r = wc1 second half (chunk-major), LDS-staged 32KB
//   blocks [RB, RB+HGRID): scatterA — packed = src|(dst&255)<<24 into
//                         contiguous per-bucket runs (no global atomics)
// The two halves are independent; the latency-bound scatter hides the GEMM.
// ===========================================================================
__global__ __launch_bounds__(TBLOCK) void scatroot_k(
    const int* __restrict__ edges, int E,
    const int* __restrict__ counts, const int* __restrict__ total,
    unsigned int* __restrict__ packed, int NBUCK,
    const ushort* __restrict__ xb, const ushort* __restrict__ wc1,
    const float* __restrict__ b1, ushort* __restrict__ hb, int N, int RB) {
    __shared__ __align__(16) ushort sW[128 * 128];   // 32 KB (gemm role)
    __shared__ int s[TBLOCK];
    __shared__ int lb[MAXBUCK];
    __shared__ int lh[MAXBUCK];
    const int t = threadIdx.x;

    if ((int)blockIdx.x < RB) {
        // ---- root GEMM: K=128 over xb, weights = wc1 + 16384 (k=128..255) --
        const ushort* wroot = wc1 + 16384;
        for (int i = t * 8; i < 128 * 128; i += TBLOCK * 8)
            *(short8*)&sW[i] = *(const short8*)&wroot[i];
        __syncthreads();
        const int wave = t >> 6;
        const int lane = t & 63;
        const int quad = lane >> 4;
        const int l16 = lane & 15;
        const int m0 = (blockIdx.x * 4 + wave) * 32;
        if (m0 >= N) return;
        f32x4 acc[2][8];
#pragma unroll
        for (int tt = 0; tt < 2; tt++)
#pragma unroll
            for (int nt = 0; nt < 8; nt++) acc[tt][nt] = (f32x4){0.f, 0.f, 0.f, 0.f};
        const int k0q = quad * 8;
#pragma unroll
        for (int kb = 0; kb < 128; kb += 32) {
            int k = kb + k0q;
            short8 a[2];
#pragma unroll
            for (int tt = 0; tt < 2; tt++) {
                int m = m0 + tt * 16 + l16;
                if (m > N - 1) m = N - 1;
                a[tt] = *(const short8*)(xb + (size_t)m * 128 + k);
            }
#pragma unroll
            for (int nt = 0; nt < 8; nt++) {
                short8 b = *(const short8*)&sW[((k >> 3) * 128 + nt * 16 + l16) * 8];
                acc[0][nt] = __builtin_amdgcn_mfma_f32_16x16x32_bf16(a[0], b, acc[0][nt], 0, 0, 0);
                acc[1][nt] = __builtin_amdgcn_mfma_f32_16x16x32_bf16(a[1], b, acc[1][nt], 0, 0, 0);
            }
        }
#pragma unroll
        for (int tt = 0; tt < 2; tt++)
#pragma unroll
            for (int r = 0; r < 4; r++) {
                int m = m0 + tt * 16 + quad * 4 + r;
                if (m >= N) continue;
#pragma unroll
                for (int nt = 0; nt < 8; nt++) {
                    int n = nt * 16 + l16;
                    hb[(size_t)m * 128 + n] = f2bf(acc[tt][nt][r] + b1[n]);
                }
            }
    } else {
        // ---- scatterA role --------------------------------------------------
        const int b = blockIdx.x - RB;
        const int is64 = block_detect_is64(edges);
        scan_total(total, NBUCK, s);
        if (t < NBUCK) {
            int excl = (t == 0) ? 0 : s[t - 1];
            lb[t] = excl + counts[t * HGRID + b];
            lh[t] = 0;
        }
        __syncthreads();
        const int per = (E + HGRID - 1) / HGRID;
        const int b0 = b * per, b1e = min(E, b0 + per);
        for (int i = b0 + t; i < b1e; i += TBLOCK) {
            int sv = load_src(edges, i, E, is64);
            int d = load_dst(edges, i, E, is64);
            int bk = d >> 8;
            int pos = lb[bk] + atomicAdd(&lh[bk], 1);
            packed[pos] = (unsigned int)sv | ((unsigned int)(d & 255) << 24);
        }
    }
}

// ---- per-bucket CSR finalize (one workgroup per bucket) -------------------
__global__ __launch_bounds__(TBLOCK) void buildB_k(const unsigned int* __restrict__ packed,
                                                   const int* __restrict__ total,
                                                   int* __restrict__ offs,
                                                   int* __restrict__ degi,
                                                   float* __restrict__ invdeg,
                                                   int* __restrict__ csr, int N, int NBUCK) {
    __shared__ int s[TBLOCK];
    __shared__ int cnt[TBLOCK], scn[TBLOCK], cur[TBLOCK];
    int t = threadIdx.x;
    int bucket = blockIdx.x;
    scan_total(total, NBUCK, s);
    int e0 = (bucket == 0) ? 0 : s[bucket - 1];
    int e1 = s[bucket];
    cnt[t] = 0;
    cur[t] = 0;
    __syncthreads();
    for (int i = e0 + t; i < e1; i += TBLOCK)
        atomicAdd(&cnt[packed[i] >> 24], 1);
    __syncthreads();
    scn[t] = cnt[t];
    __syncthreads();
    for (int off = 1; off < TBLOCK; off <<= 1) {
        int x = (t >= off) ? scn[t - off] : 0;
        __syncthreads();
        scn[t] += x;
        __syncthreads();
    }
    int excl = (t == 0) ? 0 : scn[t - 1];
    int node = bucket * 256 + t;
    if (node < N) {
        offs[node] = e0 + excl;
        degi[node] = cnt[t];
        invdeg[node] = 1.0f / fmaxf((float)cnt[t], 1.0f);
    }
    __syncthreads();
    cnt[t] = excl;               // reuse as per-node exclusive base
    __syncthreads();
    for (int i = e0 + t; i < e1; i += TBLOCK) {
        unsigned int p = packed[i];
        int nl = p >> 24;
        int pos = e0 + cnt[nl] + atomicAdd(&cur[nl], 1);
        csr[pos] = (int)(p & 0xFFFFFFu);
    }
}

// ---- gather-aggregate over bf16 features ---------------------------------
// ACCUM=0: outB[n][:] = bf16(invdeg[n] * sum feat[src])      (layer 1, C=128)
// ACCUM=1: outF[n][:] += invdeg[n] * sum feat[src]           (layer 2, C=64)
template <int C, bool ACCUM>
__global__ __launch_bounds__(TBLOCK) void gatherb_k(const ushort* __restrict__ feat,
                                                    const int* __restrict__ csr,
                                                    const int* __restrict__ offs,
                                                    const int* __restrict__ degi,
                                                    const float* __restrict__ invdeg,
                                                    ushort* __restrict__ outB,
                                                    float* __restrict__ outF, int N) {
    constexpr int G = C / 8;                  // lanes per node, 16B bf16x8 each
    constexpr int NPB = TBLOCK / G;
    int n = blockIdx.x * NPB + threadIdx.x / G;
    if (n >= N) return;
    int lane = threadIdx.x % G;
    int c = lane * 8;
    int s0 = offs[n];
    int d = degi[n];
    float acc[8] = {0.f, 0.f, 0.f, 0.f, 0.f, 0.f, 0.f, 0.f};
    for (int base = 0; base < d; base += G) {
        int rem = d - base;
        int my = (lane < rem) ? csr[s0 + base + lane] : 0;
        if (rem >= G) {
#pragma unroll
            for (int j = 0; j < G; j++) {
                int s = __shfl(my, j, G);
                short8 v = *(const short8*)(feat + (size_t)s * C + c);
#pragma unroll
                for (int q = 0; q < 8; q++) acc[q] += bf2f((ushort)v[q]);
            }
        } else {
            for (int j = 0; j < rem; j++) {
                int s = __shfl(my, j, G);
                short8 v = *(const short8*)(feat + (size_t)s * C + c);
#pragma unroll
                for (int q = 0; q < 8; q++) acc[q] += bf2f((ushort)v[q]);
            }
        }
    }
    float sc = invdeg[n];
    if (ACCUM) {
        float* o = outF + (size_t)n * C + c;
        float4 p0 = *(float4*)o;
        float4 p1 = *(float4*)(o + 4);
        p0.x += sc * acc[0]; p0.y += sc * acc[1]; p0.z += sc * acc[2]; p0.w += sc * acc[3];
        p1.x += sc * acc[4]; p1.y += sc * acc[5]; p1.z += sc * acc[6]; p1.w += sc * acc[7];
        *(float4*)o = p0;
        *(float4*)(o + 4) = p1;
    } else {
        short8 o;
#pragma unroll
        for (int q = 0; q < 8; q++) o[q] = f2bf(sc * acc[q]);
        *(short8*)(outB + (size_t)n * C + c) = o;
    }
}

// ===========================================================================
// gemm1b_k: hb = bf16(relu(agg1b @ W1l + hb)).  K=128, weights = wc1 first
// half (k=0..127, 32 KB LDS). Base hb read per-element in C-layout.
// ===========================================================================
__global__ __launch_bounds__(TBLOCK) void gemm1b_k(const ushort* __restrict__ agg1b,
                                                   const ushort* __restrict__ wc1,
                                                   ushort* __restrict__ hb, int N) {
    __shared__ __align__(16) ushort sW[128 * 128];
    for (int i = threadIdx.x * 8; i < 128 * 128; i += TBLOCK * 8)
        *(short8*)&sW[i] = *(const short8*)&wc1[i];
    __syncthreads();

    const int wave = threadIdx.x >> 6;
    const int lane = threadIdx.x & 63;
    const int quad = lane >> 4;
    const int l16 = lane & 15;
    const int m0 = (blockIdx.x * 4 + wave) * 32;
    if (m0 >= N) return;

    f32x4 acc[2][8];
#pragma unroll
    for (int t = 0; t < 2; t++)
#pragma unroll
        for (int nt = 0; nt < 8; nt++) acc[t][nt] = (f32x4){0.f, 0.f, 0.f, 0.f};

    const int k0q = quad * 8;
#pragma unroll
    for (int kb = 0; kb < 128; kb += 32) {
        int k = kb + k0q;
        short8 a[2];
#pragma unroll
        for (int t = 0; t < 2; t++) {
            int m = m0 + t * 16 + l16;
            if (m > N - 1) m = N - 1;
            a[t] = *(const short8*)(agg1b + (size_t)m * 128 + k);
        }
#pragma unroll
        for (int nt = 0; nt < 8; nt++) {
            short8 b = *(const short8*)&sW[((k >> 3) * 128 + nt * 16 + l16) * 8];
            acc[0][nt] = __builtin_amdgcn_mfma_f32_16x16x32_bf16(a[0], b, acc[0][nt], 0, 0, 0);
            acc[1][nt] = __builtin_amdgcn_mfma_f32_16x16x32_bf16(a[1], b, acc[1][nt], 0, 0, 0);
        }
    }

#pragma unroll
    for (int t = 0; t < 2; t++) {
#pragma unroll
        for (int r = 0; r < 4; r++) {
            int m = m0 + t * 16 + quad * 4 + r;
            if (m >= N) continue;
#pragma unroll
            for (int nt = 0; nt < 8; nt++) {
                int n = nt * 16 + l16;
                float v = acc[t][nt][r] + bf2f(hb[(size_t)m * 128 + n]);
                hb[(size_t)m * 128 + n] = f2bf(fmaxf(v, 0.f));
            }
        }
    }
}

// ---- MFMA bf16 GEMM layer 2: [N x 128] @ [128 x 128], weights in LDS ------
// n<64 -> t2b = bf16(acc); n>=64 -> out = acc + b2[n-64] (fp32)
__global__ __launch_bounds__(TBLOCK) void gemm2_k(const ushort* __restrict__ A0,
                                                  const ushort* __restrict__ wc,
                                                  const float* __restrict__ bias,
                                                  ushort* __restrict__ outB,
                                                  float* __restrict__ outF, int N) {
    constexpr int KTOT = 128;
    __shared__ __align__(16) ushort sW[KTOT * 128];
    for (int i = threadIdx.x * 8; i < KTOT * 128; i += TBLOCK * 8)
        *(short8*)&sW[i] = *(const short8*)&wc[i];
    __syncthreads();

    const int wave = threadIdx.x >> 6;
    const int lane = threadIdx.x & 63;
    const int quad = lane >> 4;
    const int l16 = lane & 15;
    const int m0 = (blockIdx.x * 4 + wave) * 32;
    if (m0 >= N) return;

    f32x4 acc[2][8];
#pragma unroll
    for (int t = 0; t < 2; t++)
#pragma unroll
        for (int nt = 0; nt < 8; nt++) acc[t][nt] = (f32x4){0.f, 0.f, 0.f, 0.f};

    const int k0q = quad * 8;
#pragma unroll
    for (int kb = 0; kb < KTOT; kb += 32) {
        int k = kb + k0q;
        short8 a[2];
#pragma unroll
        for (int t = 0; t < 2; t++) {
            int m = m0 + t * 16 + l16;
            if (m > N - 1) m = N - 1;
            a[t] = *(const short8*)(A0 + (size_t)m * 128 + k);
        }
#pragma unroll
        for (int nt = 0; nt < 8; nt++) {
            short8 b = *(const short8*)&sW[((k >> 3) * 128 + nt * 16 + l16) * 8];
            acc[0][nt] = __builtin_amdgcn_mfma_f32_16x16x32_bf16(a[0], b, acc[0][nt], 0, 0, 0);
            acc[1][nt] = __builtin_amdgcn_mfma_f32_16x16x32_bf16(a[1], b, acc[1][nt], 0, 0, 0);
        }
    }

#pragma unroll
    for (int t = 0; t < 2; t++) {
#pragma unroll
        for (int r = 0; r < 4; r++) {
            int m = m0 + t * 16 + quad * 4 + r;
            if (m >= N) continue;
#pragma unroll
            for (int nt = 0; nt < 8; nt++) {
                int n = nt * 16 + l16;
                float v = acc[t][nt][r];
                if (n < 64) outB[(size_t)m * 64 + n] = f2bf(v);
                else outF[(size_t)m * 64 + (n - 64)] = v + bias[n - 64];
            }
        }
    }
}

extern "C" void kernel_launch(void* const* d_in, const int* in_sizes, int n_in,
                              void* d_out, int out_size, void* d_ws, size_t ws_size,
                              hipStream_t stream) {
    const float* x = (const float*)d_in[0];
    const int* edges = (const int*)d_in[1];
    const float* W1l = (const float*)d_in[2];
    const float* b1 = (const float*)d_in[3];
    const float* W1r = (const float*)d_in[4];
    const float* W2l = (const float*)d_in[5];
    const float* b2 = (const float*)d_in[6];
    const float* W2r = (const float*)d_in[7];
    float* out = (float*)d_out;

    const int N = in_sizes[0] / 128;   // 50000
    const int E = in_sizes[1] / 2;     // 800000
    const int Na = (N + 63) & ~63;
    const int NBUCK = (N + 255) >> 8;  // 196 (in-block scans require <= 256)
    const int n8 = N * 128 / 8;
    const int nxb = (n8 + TBLOCK - 1) / TBLOCK;
    const int RB = (N + 127) / 128;    // root-gemm blocks in scatroot

    // ---- workspace layout (bytes, 256B-aligned regions) ----
    char* WS = (char*)d_ws;
    size_t off = 0;
    auto alloc = [&](size_t bytes) {
        void* p = WS + off;
        off = (off + bytes + 255) & ~(size_t)255;
        return p;
    };
    int* counts = (int*)alloc((size_t)MAXBUCK * HGRID * 4);  // per-(bucket,block)
    int* total = (int*)alloc((size_t)MAXBUCK * 4);
    int* offs = (int*)alloc((size_t)Na * 4);
    int* degi = (int*)alloc((size_t)Na * 4);
    float* invdeg = (float*)alloc((size_t)Na * 4);
    unsigned int* packed = (unsigned int*)alloc((size_t)E * 4);
    int* csr = (int*)alloc((size_t)E * 4);
    ushort* xb = (ushort*)alloc((size_t)N * 128 * 2);
    ushort* agg1b = (ushort*)alloc((size_t)N * 128 * 2);
    ushort* hb = (ushort*)alloc((size_t)N * 128 * 2);
    ushort* t2b = (ushort*)alloc((size_t)N * 64 * 2);
    ushort* wc1 = (ushort*)alloc(32768 * 2);
    ushort* wc2 = (ushort*)alloc(16384 * 2);

    // ---- build + prep ----
    histprep_k<<<HGRID + nxb + 192, TBLOCK, 0, stream>>>(
        x, W1l, W1r, W2l, W2r, edges, E, NBUCK, xb, wc1, wc2, counts, n8, nxb);
    scanA_k<<<NBUCK, TBLOCK, 0, stream>>>(counts, total);
    // overlapped: root gemm (hb = xb@W1r + b1) + packed scatter
    scatroot_k<<<RB + HGRID, TBLOCK, 0, stream>>>(
        edges, E, counts, total, packed, NBUCK, xb, wc1, b1, hb, N, RB);
    buildB_k<<<NBUCK, TBLOCK, 0, stream>>>(packed, total, offs, degi, invdeg, csr, N, NBUCK);

    // layer 1: agg1b = bf16(mean_agg(xb))
    gatherb_k<128, false><<<(N + 15) / 16, TBLOCK, 0, stream>>>(
        xb, csr, offs, degi, invdeg, agg1b, nullptr, N);
    // hb = bf16(relu(agg1b @ W1l + hb))
    gemm1b_k<<<(N + 127) / 128, TBLOCK, 0, stream>>>(agg1b, wc1, hb, N);

    // layer 2: t2b = bf16(hb @ W2l); out = hb @ W2r + b2
    gemm2_k<<<(N + 127) / 128, TBLOCK, 0, stream>>>(
        hb, wc2, b2, t2b, out, N);
    // out += mean_agg(t2b)
    gatherb_k<64, true><<<(N + 31) / 32, TBLOCK, 0, stream>>>(
        t2b, csr, offs, degi, invdeg, nullptr, out, N);
}

// Round 13
// 187.787 us; speedup vs baseline: 1.1282x; 1.0339x over previous
//
#include <hip/hip_runtime.h>
#include <hip/hip_bf16.h>

// GraphSAGE 2-layer on MI355X.
//   h   = relu(mean_agg(x) @ W1l + b1 + x @ W1r)
//   out = mean_agg(h @ W2l) + b2 + h @ W2r          (aggregate AFTER transform: 64ch)
// R2: CSR-gather replaced atomic scatter (2302 -> 387 us).
// R3: bf16 gathers + MFMA bf16 GEMMs (387 -> 253 us).
// R4/R5: bucketed CSR build, wide grid (253 -> 216 us).
// R6 FAILED: cooperative fusion; grid.sync() ~55 us each on 8 XCDs.
// R7/R8: zero-atomic counts-matrix build + parallel scan (216 -> 194 us).
// R9 FAILED: gemm with L2-streamed weights (weights must be LDS-resident).
// R11 FAILED: gather fused into gemm block (occupancy + uncoalesced gather).
// R12: role-split root GEMM under scatterA (neutral: hb RMW offset the win).
// R13: gemm1b+gemm2 fused into gemm12_k — same 128-row tile, hb tile lives in
//     LDS (34KB, never written to global), weights staged into ONE 32KB LDS
//     region (W1l, then restaged wc2 after a barrier). -1 dispatch, -25.6 MB.

#define TBLOCK 256
#define MAXBUCK 256    // in-block total-scan requires NBUCK <= 256 (N <= 65536)
#define HGRID 512      // edge-processing blocks (2/CU)
#define HPAD 136       // hb LDS tile row stride (8-ushort pad, 16B-aligned rows)

typedef __attribute__((ext_vector_type(8))) short short8;
typedef __attribute__((ext_vector_type(4))) float f32x4;

__device__ __forceinline__ float bf2f(ushort u) {
    union { unsigned int i; float f; } v;
    v.i = (unsigned int)u << 16;
    return v.f;
}
__device__ __forceinline__ ushort f2bf(float f) {  // RTNE
    union { float f; unsigned int u; } v;
    v.f = f;
    unsigned int r = v.u + 0x7fffu + ((v.u >> 16) & 1u);
    return (ushort)(r >> 16);
}

// ---- per-block edge-index dtype detection (int32 vs int64) ----------------
// int64 little-endian with values < 2^31 => every odd int32 word is zero.
__device__ __forceinline__ int block_detect_is64(const int* __restrict__ edges) {
    __shared__ int sbad[4];
    int tid = threadIdx.x;
    int bad = 0;
    for (int i = tid; i < 2048; i += TBLOCK)
        if (edges[2 * i + 1] != 0) bad = 1;
    unsigned long long b = __ballot(bad);
    if ((tid & 63) == 0) sbad[tid >> 6] = (b != 0) ? 1 : 0;
    __syncthreads();
    int flag = (sbad[0] | sbad[1] | sbad[2] | sbad[3]) ? 0 : 1;
    __syncthreads();
    return flag;
}

__device__ __forceinline__ int load_src(const int* e, long long i, int E, int is64) {
    return is64 ? e[2 * i] : e[i];
}
__device__ __forceinline__ int load_dst(const int* e, long long i, int E, int is64) {
    return is64 ? e[2 * (long long)E + 2 * i] : e[(long long)E + i];
}

// ---- in-block inclusive scan of bucket totals (NBUCK <= 256) --------------
__device__ __forceinline__ void scan_total(const int* __restrict__ total, int NBUCK,
                                           int* __restrict__ s) {
    int t = threadIdx.x;
    s[t] = (t < NBUCK) ? total[t] : 0;
    __syncthreads();
    for (int off = 1; off < TBLOCK; off <<= 1) {
        int xv = (t >= off) ? s[t - off] : 0;
        __syncthreads();
        s[t] += xv;
        __syncthreads();
    }
    // s[t] now holds inclusive prefix sums
}

// ===========================================================================
// histprep_k: blocks [0,HGRID) do the bucket histogram (bucket = dst>>8) and
// store per-block counts NON-ATOMICALLY to counts[j*HGRID + b] (no pre-zero
// needed). Blocks >= HGRID do prep: x -> bf16 xb, weight transpose/concat.
// wc[((k>>3)*128 + n)*8 + (k&7)] = W[k][n] (chunk-major for MFMA B-frags)
// wc1: K=256 = [W1l; W1r], N=128.  wc2: K=128, N=128 = [W2l | W2r].
// ===========================================================================
__global__ __launch_bounds__(TBLOCK) void histprep_k(
    const float* __restrict__ x,
    const float* __restrict__ W1l, const float* __restrict__ W1r,
    const float* __restrict__ W2l, const float* __restrict__ W2r,
    const int* __restrict__ edges, int E, int NBUCK,
    ushort* __restrict__ xb, ushort* __restrict__ wc1, ushort* __restrict__ wc2,
    int* __restrict__ counts, int n8, int nxb) {
    __shared__ int lh[MAXBUCK];
    const int b = blockIdx.x;
    const int t = threadIdx.x;
    if (b < HGRID) {
        const int is64 = block_detect_is64(edges);
        for (int i = t; i < NBUCK; i += TBLOCK) lh[i] = 0;
        __syncthreads();
        const int per = (E + HGRID - 1) / HGRID;
        const int b0 = b * per, b1 = min(E, b0 + per);
        for (int i = b0 + t; i < b1; i += TBLOCK)
            atomicAdd(&lh[load_dst(edges, i, E, is64) >> 8], 1);
        __syncthreads();
        for (int j = t; j < NBUCK; j += TBLOCK)
            counts[j * HGRID + b] = lh[j];
    } else {
        int pb = b - HGRID;
        if (pb < nxb) {
            int i = pb * TBLOCK + t;
            if (i >= n8) return;
            const float4* p = (const float4*)x + (size_t)i * 2;
            float4 a = p[0], bb = p[1];
            short8 o;
            o[0] = f2bf(a.x); o[1] = f2bf(a.y); o[2] = f2bf(a.z); o[3] = f2bf(a.w);
            o[4] = f2bf(bb.x); o[5] = f2bf(bb.y); o[6] = f2bf(bb.z); o[7] = f2bf(bb.w);
            *(short8*)(xb + (size_t)i * 8) = o;
        } else {
            int i = (pb - nxb) * TBLOCK + t;
            if (i < 32768) {
                int j = i & 7;
                int rest = i >> 3;
                int n = rest & 127;
                int k = ((rest >> 7) << 3) | j;
                float w = (k < 128) ? W1l[k * 128 + n] : W1r[(k - 128) * 128 + n];
                wc1[i] = f2bf(w);
            } else if (i < 49152) {
                int i2 = i - 32768;
                int j = i2 & 7;
                int rest = i2 >> 3;
                int n = rest & 127;
                int k = ((rest >> 7) << 3) | j;
                float w = (n < 64) ? W2l[k * 64 + n] : W2r[k * 64 + (n - 64)];
                wc2[i2] = f2bf(w);
            }
        }
    }
}

// ===========================================================================
// scanA_k: one block per bucket. Parallel exclusive scan of the bucket's
// HGRID per-block counts (2/thread via LDS), rewrite row in place as LOCAL
// exclusive prefixes, write bucket total.
// ===========================================================================
__global__ __launch_bounds__(TBLOCK) void scanA_k(int* __restrict__ counts,
                                                  int* __restrict__ total) {
    __shared__ int s[TBLOCK];
    const int j = blockIdx.x;
    const int t = threadIdx.x;
    int* row = counts + (size_t)j * HGRID;
    int v0 = row[2 * t];
    int v1 = row[2 * t + 1];
    s[t] = v0 + v1;
    __syncthreads();
    for (int off = 1; off < TBLOCK; off <<= 1) {
        int xv = (t >= off) ? s[t - off] : 0;
        __syncthreads();
        s[t] += xv;
        __syncthreads();
    }
    int excl = (t == 0) ? 0 : s[t - 1];
    row[2 * t] = excl;
    row[2 * t + 1] = excl + v0;
    if (t == TBLOCK - 1) total[j] = s[t];
}

// ===========================================================================
// scatroot_k (role-split, overlapped):
//   blocks [0, RB):       root GEMM  hb = bf16(xb @ W1r + b1)   (no relu yet)
//                         W1r = wc1 second half (chunk-major), LDS-staged 32KB
//   blocks [RB, RB+HGRID): scatterA — packed = src|(dst&255)<<24 into
//                         contiguous per-bucket runs (no global atomics)
// The two halves are independent; the latency-bound scatter hides the GEMM.
// ===========================================================================
__global__ __launch_bounds__(TBLOCK) void scatroot_k(
    const int* __restrict__ edges, int E,
    const int* __restrict__ counts, const int* __restrict__ total,
    unsigned int* __restrict__ packed, int NBUCK,
    const ushort* __restrict__ xb, const ushort* __restrict__ wc1,
    const float* __restrict__ b1, ushort* __restrict__ hb, int N, int RB) {
    __shared__ __align__(16) ushort sW[128 * 128];   // 32 KB (gemm role)
    __shared__ int s[TBLOCK];
    __shared__ int lb[MAXBUCK];
    __shared__ int lh[MAXBUCK];
    const int t = threadIdx.x;

    if ((int)blockIdx.x < RB) {
        // ---- root GEMM: K=128 over xb, weights = wc1 + 16384 (k=128..255) --
        const ushort* wroot = wc1 + 16384;
        for (int i = t * 8; i < 128 * 128; i += TBLOCK * 8)
            *(short8*)&sW[i] = *(const short8*)&wroot[i];
        __syncthreads();
        const int wave = t >> 6;
        const int lane = t & 63;
        const int quad = lane >> 4;
        const int l16 = lane & 15;
        const int m0 = (blockIdx.x * 4 + wave) * 32;
        if (m0 >= N) return;
        f32x4 acc[2][8];
#pragma unroll
        for (int tt = 0; tt < 2; tt++)
#pragma unroll
            for (int nt = 0; nt < 8; nt++) acc[tt][nt] = (f32x4){0.f, 0.f, 0.f, 0.f};
        const int k0q = quad * 8;
#pragma unroll
        for (int kb = 0; kb < 128; kb += 32) {
            int k = kb + k0q;
            short8 a[2];
#pragma unroll
            for (int tt = 0; tt < 2; tt++) {
                int m = m0 + tt * 16 + l16;
                if (m > N - 1) m = N - 1;
                a[tt] = *(const short8*)(xb + (size_t)m * 128 + k);
            }
#pragma unroll
            for (int nt = 0; nt < 8; nt++) {
                short8 b = *(const short8*)&sW[((k >> 3) * 128 + nt * 16 + l16) * 8];
                acc[0][nt] = __builtin_amdgcn_mfma_f32_16x16x32_bf16(a[0], b, acc[0][nt], 0, 0, 0);
                acc[1][nt] = __builtin_amdgcn_mfma_f32_16x16x32_bf16(a[1], b, acc[1][nt], 0, 0, 0);
            }
        }
#pragma unroll
        for (int tt = 0; tt < 2; tt++)
#pragma unroll
            for (int r = 0; r < 4; r++) {
                int m = m0 + tt * 16 + quad * 4 + r;
                if (m >= N) continue;
#pragma unroll
                for (int nt = 0; nt < 8; nt++) {
                    int n = nt * 16 + l16;
                    hb[(size_t)m * 128 + n] = f2bf(acc[tt][nt][r] + b1[n]);
                }
            }
    } else {
        // ---- scatterA role --------------------------------------------------
        const int b = blockIdx.x - RB;
        const int is64 = block_detect_is64(edges);
        scan_total(total, NBUCK, s);
        if (t < NBUCK) {
            int excl = (t == 0) ? 0 : s[t - 1];
            lb[t] = excl + counts[t * HGRID + b];
            lh[t] = 0;
        }
        __syncthreads();
        const int per = (E + HGRID - 1) / HGRID;
        const int b0 = b * per, b1e = min(E, b0 + per);
        for (int i = b0 + t; i < b1e; i += TBLOCK) {
            int sv = load_src(edges, i, E, is64);
            int d = load_dst(edges, i, E, is64);
            int bk = d >> 8;
            int pos = lb[bk] + atomicAdd(&lh[bk], 1);
            packed[pos] = (unsigned int)sv | ((unsigned int)(d & 255) << 24);
        }
    }
}

// ---- per-bucket CSR finalize (one workgroup per bucket) -------------------
__global__ __launch_bounds__(TBLOCK) void buildB_k(const unsigned int* __restrict__ packed,
                                                   const int* __restrict__ total,
                                                   int* __restrict__ offs,
                                                   int* __restrict__ degi,
                                                   float* __restrict__ invdeg,
                                                   int* __restrict__ csr, int N, int NBUCK) {
    __shared__ int s[TBLOCK];
    __shared__ int cnt[TBLOCK], scn[TBLOCK], cur[TBLOCK];
    int t = threadIdx.x;
    int bucket = blockIdx.x;
    scan_total(total, NBUCK, s);
    int e0 = (bucket == 0) ? 0 : s[bucket - 1];
    int e1 = s[bucket];
    cnt[t] = 0;
    cur[t] = 0;
    __syncthreads();
    for (int i = e0 + t; i < e1; i += TBLOCK)
        atomicAdd(&cnt[packed[i] >> 24], 1);
    __syncthreads();
    scn[t] = cnt[t];
    __syncthreads();
    for (int off = 1; off < TBLOCK; off <<= 1) {
        int x = (t >= off) ? scn[t - off] : 0;
        __syncthreads();
        scn[t] += x;
        __syncthreads();
    }
    int excl = (t == 0) ? 0 : scn[t - 1];
    int node = bucket * 256 + t;
    if (node < N) {
        offs[node] = e0 + excl;
        degi[node] = cnt[t];
        invdeg[node] = 1.0f / fmaxf((float)cnt[t], 1.0f);
    }
    __syncthreads();
    cnt[t] = excl;               // reuse as per-node exclusive base
    __syncthreads();
    for (int i = e0 + t; i < e1; i += TBLOCK) {
        unsigned int p = packed[i];
        int nl = p >> 24;
        int pos = e0 + cnt[nl] + atomicAdd(&cur[nl], 1);
        csr[pos] = (int)(p & 0xFFFFFFu);
    }
}

// ---- gather-aggregate over bf16 features ---------------------------------
// ACCUM=0: outB[n][:] = bf16(invdeg[n] * sum feat[src])      (layer 1, C=128)
// ACCUM=1: outF[n][:] += invdeg[n] * sum feat[src]           (layer 2, C=64)
template <int C, bool ACCUM>
__global__ __launch_bounds__(TBLOCK) void gatherb_k(const ushort* __restrict__ feat,
                                                    const int* __restrict__ csr,
                                                    const int* __restrict__ offs,
                                                    const int* __restrict__ degi,
                                                    const float* __restrict__ invdeg,
                                                    ushort* __restrict__ outB,
                                                    float* __restrict__ outF, int N) {
    constexpr int G = C / 8;                  // lanes per node, 16B bf16x8 each
    constexpr int NPB = TBLOCK / G;
    int n = blockIdx.x * NPB + threadIdx.x / G;
    if (n >= N) return;
    int lane = threadIdx.x % G;
    int c = lane * 8;
    int s0 = offs[n];
    int d = degi[n];
    float acc[8] = {0.f, 0.f, 0.f, 0.f, 0.f, 0.f, 0.f, 0.f};
    for (int base = 0; base < d; base += G) {
        int rem = d - base;
        int my = (lane < rem) ? csr[s0 + base + lane] : 0;
        if (rem >= G) {
#pragma unroll
            for (int j = 0; j < G; j++) {
                int s = __shfl(my, j, G);
                short8 v = *(const short8*)(feat + (size_t)s * C + c);
#pragma unroll
                for (int q = 0; q < 8; q++) acc[q] += bf2f((ushort)v[q]);
            }
        } else {
            for (int j = 0; j < rem; j++) {
                int s = __shfl(my, j, G);
                short8 v = *(const short8*)(feat + (size_t)s * C + c);
#pragma unroll
                for (int q = 0; q < 8; q++) acc[q] += bf2f((ushort)v[q]);
            }
        }
    }
    float sc = invdeg[n];
    if (ACCUM) {
        float* o = outF + (size_t)n * C + c;
        float4 p0 = *(float4*)o;
        float4 p1 = *(float4*)(o + 4);
        p0.x += sc * acc[0]; p0.y += sc * acc[1]; p0.z += sc * acc[2]; p0.w += sc * acc[3];
        p1.x += sc * acc[4]; p1.y += sc * acc[5]; p1.z += sc * acc[6]; p1.w += sc * acc[7];
        *(float4*)o = p0;
        *(float4*)(o + 4) = p1;
    } else {
        short8 o;
#pragma unroll
        for (int q = 0; q < 8; q++) o[q] = f2bf(sc * acc[q]);
        *(short8*)(outB + (size_t)n * C + c) = o;
    }
}

// ===========================================================================
// gemm12_k: fused layers over one 128-row tile.
//   L1: hbt(LDS) = bf16(relu(agg1b @ W1l + hbB))     (hbB = xb@W1r+b1, global)
//   L2: n<64 -> t2b = bf16(hbt @ W2l); n>=64 -> out = hbt @ W2r + b2
// ONE 32KB LDS weight buffer: W1l staged, used, then restaged with wc2 after
// a barrier. hb tile never touches global (saves 25.6 MB vs R12).
// mfma_f32_16x16x32_bf16 layouts (m89/m91):
//   A frag: lane L holds A[m=L&15][k=(L>>4)*8+j]; B frag: B[k=(L>>4)*8+j][n=L&15]
//   C/D: reg r -> row=(L>>4)*4+r, col=L&15
// ===========================================================================
__global__ __launch_bounds__(TBLOCK) void gemm12_k(const ushort* __restrict__ agg1b,
                                                   const ushort* __restrict__ wc1,
                                                   const ushort* __restrict__ wc2,
                                                   const ushort* __restrict__ hbB,
                                                   const float* __restrict__ b2,
                                                   ushort* __restrict__ t2b,
                                                   float* __restrict__ outF, int N) {
    __shared__ __align__(16) ushort sW[128 * 128];   // 32 KB, W1l then wc2
    __shared__ __align__(16) ushort hbt[128 * HPAD]; // 34 KB hb tile
    const int t = threadIdx.x;
    const int wave = t >> 6;
    const int lane = t & 63;
    const int quad = lane >> 4;
    const int l16 = lane & 15;
    const int m0 = blockIdx.x * 128 + wave * 32;
    const int k0q = quad * 8;

    // ---- stage W1l (wc1 first half: k=0..127) ----
    for (int i = t * 8; i < 128 * 128; i += TBLOCK * 8)
        *(short8*)&sW[i] = *(const short8*)&wc1[i];
    __syncthreads();

    // ---- layer 1: K=128 over agg1b ----
    f32x4 acc[2][8];
#pragma unroll
    for (int tt = 0; tt < 2; tt++)
#pragma unroll
        for (int nt = 0; nt < 8; nt++) acc[tt][nt] = (f32x4){0.f, 0.f, 0.f, 0.f};
#pragma unroll
    for (int kb = 0; kb < 128; kb += 32) {
        int k = kb + k0q;
        short8 a[2];
#pragma unroll
        for (int tt = 0; tt < 2; tt++) {
            int m = m0 + tt * 16 + l16;
            if (m > N - 1) m = N - 1;
            a[tt] = *(const short8*)(agg1b + (size_t)m * 128 + k);
        }
#pragma unroll
        for (int nt = 0; nt < 8; nt++) {
            short8 b = *(const short8*)&sW[((k >> 3) * 128 + nt * 16 + l16) * 8];
            acc[0][nt] = __builtin_amdgcn_mfma_f32_16x16x32_bf16(a[0], b, acc[0][nt], 0, 0, 0);
            acc[1][nt] = __builtin_amdgcn_mfma_f32_16x16x32_bf16(a[1], b, acc[1][nt], 0, 0, 0);
        }
    }

    // ---- epilogue 1: hbt = bf16(relu(acc + hbB[m])) (LDS only) ----
#pragma unroll
    for (int tt = 0; tt < 2; tt++)
#pragma unroll
        for (int r = 0; r < 4; r++) {
            int ml = wave * 32 + tt * 16 + quad * 4 + r;   // local row
            int m = m0 + tt * 16 + quad * 4 + r;
            int mc = (m < N) ? m : N - 1;                   // clamp global read
#pragma unroll
            for (int nt = 0; nt < 8; nt++) {
                int n = nt * 16 + l16;
                float v = acc[tt][nt][r] + bf2f(hbB[(size_t)mc * 128 + n]);
                hbt[ml * HPAD + n] = f2bf(fmaxf(v, 0.f));
            }
        }
    __syncthreads();                      // layer-1 sW reads done, hbt complete

    // ---- restage sW with wc2 ----
    for (int i = t * 8; i < 128 * 128; i += TBLOCK * 8)
        *(short8*)&sW[i] = *(const short8*)&wc2[i];
    __syncthreads();

    // ---- layer 2: K=128 over LDS hb tile ----
    f32x4 acc2[2][8];
#pragma unroll
    for (int tt = 0; tt < 2; tt++)
#pragma unroll
        for (int nt = 0; nt < 8; nt++) acc2[tt][nt] = (f32x4){0.f, 0.f, 0.f, 0.f};
#pragma unroll
    for (int kb = 0; kb < 128; kb += 32) {
        int k = kb + k0q;
        short8 a[2];
#pragma unroll
        for (int tt = 0; tt < 2; tt++)
            a[tt] = *(const short8*)&hbt[(wave * 32 + tt * 16 + l16) * HPAD + k];
#pragma unroll
        for (int nt = 0; nt < 8; nt++) {
            short8 b = *(const short8*)&sW[((k >> 3) * 128 + nt * 16 + l16) * 8];
            acc2[0][nt] = __builtin_amdgcn_mfma_f32_16x16x32_bf16(a[0], b, acc2[0][nt], 0, 0, 0);
            acc2[1][nt] = __builtin_amdgcn_mfma_f32_16x16x32_bf16(a[1], b, acc2[1][nt], 0, 0, 0);
        }
    }

    // ---- epilogue 2: n<64 -> t2b (bf16); n>=64 -> out = acc + b2 (fp32) ----
#pragma unroll
    for (int tt = 0; tt < 2; tt++)
#pragma unroll
        for (int r = 0; r < 4; r++) {
            int m = m0 + tt * 16 + quad * 4 + r;
            if (m >= N) continue;
#pragma unroll
            for (int nt = 0; nt < 8; nt++) {
                int n = nt * 16 + l16;
                float v = acc2[tt][nt][r];
                if (n < 64) t2b[(size_t)m * 64 + n] = f2bf(v);
                else outF[(size_t)m * 64 + (n - 64)] = v + b2[n - 64];
            }
        }
}

extern "C" void kernel_launch(void* const* d_in, const int* in_sizes, int n_in,
                              void* d_out, int out_size, void* d_ws, size_t ws_size,
                              hipStream_t stream) {
    const float* x = (const float*)d_in[0];
    const int* edges = (const int*)d_in[1];
    const float* W1l = (const float*)d_in[2];
    const float* b1 = (const float*)d_in[3];
    const float* W1r = (const float*)d_in[4];
    const float* W2l = (const float*)d_in[5];
    const float* b2 = (const float*)d_in[6];
    const float* W2r = (const float*)d_in[7];
    float* out = (float*)d_out;

    const int N = in_sizes[0] / 128;   // 50000
    const int E = in_sizes[1] / 2;     // 800000
    const int Na = (N + 63) & ~63;
    const int NBUCK = (N + 255) >> 8;  // 196 (in-block scans require <= 256)
    const int n8 = N * 128 / 8;
    const int nxb = (n8 + TBLOCK - 1) / TBLOCK;
    const int RB = (N + 127) / 128;    // root-gemm blocks in scatroot

    // ---- workspace layout (bytes, 256B-aligned regions) ----
    char* WS = (char*)d_ws;
    size_t off = 0;
    auto alloc = [&](size_t bytes) {
        void* p = WS + off;
        off = (off + bytes + 255) & ~(size_t)255;
        return p;
    };
    int* counts = (int*)alloc((size_t)MAXBUCK * HGRID * 4);  // per-(bucket,block)
    int* total = (int*)alloc((size_t)MAXBUCK * 4);
    int* offs = (int*)alloc((size_t)Na * 4);
    int* degi = (int*)alloc((size_t)Na * 4);
    float* invdeg = (float*)alloc((size_t)Na * 4);
    unsigned int* packed = (unsigned int*)alloc((size_t)E * 4);
    int* csr = (int*)alloc((size_t)E * 4);
    ushort* xb = (ushort*)alloc((size_t)N * 128 * 2);
    ushort* agg1b = (ushort*)alloc((size_t)N * 128 * 2);
    ushort* hb = (ushort*)alloc((size_t)N * 128 * 2);
    ushort* t2b = (ushort*)alloc((size_t)N * 64 * 2);
    ushort* wc1 = (ushort*)alloc(32768 * 2);
    ushort* wc2 = (ushort*)alloc(16384 * 2);

    // ---- build + prep ----
    histprep_k<<<HGRID + nxb + 192, TBLOCK, 0, stream>>>(
        x, W1l, W1r, W2l, W2r, edges, E, NBUCK, xb, wc1, wc2, counts, n8, nxb);
    scanA_k<<<NBUCK, TBLOCK, 0, stream>>>(counts, total);
    // overlapped: root gemm (hb = xb@W1r + b1) + packed scatter
    scatroot_k<<<RB + HGRID, TBLOCK, 0, stream>>>(
        edges, E, counts, total, packed, NBUCK, xb, wc1, b1, hb, N, RB);
    buildB_k<<<NBUCK, TBLOCK, 0, stream>>>(packed, total, offs, degi, invdeg, csr, N, NBUCK);

    // layer 1: agg1b = bf16(mean_agg(xb))
    gatherb_k<128, false><<<(N + 15) / 16, TBLOCK, 0, stream>>>(
        xb, csr, offs, degi, invdeg, agg1b, nullptr, N);
    // fused layers: hbt(LDS) = relu(agg1b@W1l + hb); t2b = hbt@W2l; out = hbt@W2r+b2
    gemm12_k<<<(N + 127) / 128, TBLOCK, 0, stream>>>(
        agg1b, wc1, wc2, hb, b2, t2b, out, N);
    // out += mean_agg(t2b)
    gatherb_k<64, true><<<(N + 31) / 32, TBLOCK, 0, stream>>>(
        t2b, csr, offs, degi, invdeg, nullptr, out, N);
}